// Round 3
// baseline (430.749 us; speedup 1.0000x reference)
//
#include <hip/hip_runtime.h>
#include <hip/hip_bf16.h>

// NestedAttnProcessor: B=2, HW=4096, hid=1280, cad=2048, Ltxt=77, NT=4, H=20, D=64.
// FP32 in/out; bf16 MFMA internally.
// 4 launches: prep(cvt+transpose) -> gemm_q_kv -> attn -> out GEMM.
// Attention fold: out = sum_{t!=s} w_t v_t + w_s * sum_j wn_j vn_j.
// R7 vs R6: gemm_body rewritten as BARRIER-FREE direct-register GEMM. R5/R6 showed
//           LDS-staged pipelines stuck at ~55us with nothing saturated (FETCH=one-pass
//           ideal, L2 ~14us worth of traffic, MfmaUtil 23%) -> per-step s_barrier
//           convoy + LDS round-trip was the structural overhead. Now each wave reads
//           A/B fragments straight from global (L2-hot, 16x64B lines per instr,
//           perfectly coalesced), double-buffered in registers, no LDS, no syncs;
//           latency hidden by 2880 independent waves (~2.8/SIMD @ ~155 VGPR).

typedef unsigned short ushort_t;
typedef __attribute__((ext_vector_type(8))) short short8;
typedef __attribute__((ext_vector_type(4))) float f32x4;

#define B_   2
#define HW_  4096
#define HID_ 1280
#define CAD_ 2048
#define LTXT 77
#define NTOK 4
#define NH_  20
#define HD_  64

__device__ __forceinline__ ushort_t f2bf(float f) {
    __hip_bfloat16 h = __float2bfloat16(f);
    return *reinterpret_cast<ushort_t*>(&h);
}

// ---------------- prep: cvt hs, cvt enc, transpose+cvt 6 weights ----------------
// grid (2560, 8): y=0 hs cvt (grid-stride), y=1 enc cvt (grid-stride),
//                 y=2..7 weight transpose (z=y-2).
__global__ __launch_bounds__(256) void prep(
    const float* __restrict__ hs, const float* __restrict__ enc,
    const float* __restrict__ s0, const float* __restrict__ s1,
    const float* __restrict__ s2, const float* __restrict__ s3,
    const float* __restrict__ s4, const float* __restrict__ s5,
    ushort_t* __restrict__ hsb, ushort_t* __restrict__ encb,
    ushort_t* __restrict__ d0, ushort_t* __restrict__ d1,
    ushort_t* __restrict__ d2, ushort_t* __restrict__ d3,
    ushort_t* __restrict__ d4, ushort_t* __restrict__ d5)
{
    const int y = blockIdx.y, t = threadIdx.x;
    if (y <= 1) {
        const float* src = y ? enc : hs;
        ushort_t* dst = y ? encb : hsb;
        int n4 = y ? (B_ * (LTXT + NTOK) * CAD_) / 4 : (B_ * HW_ * HID_) / 4;
        int step = gridDim.x * 256;
        for (int i = blockIdx.x * 256 + t; i < n4; i += step) {
            float4 v = *(const float4*)(src + (size_t)i * 4);
            ushort_t o[4] = { f2bf(v.x), f2bf(v.y), f2bf(v.z), f2bf(v.w) };
            *(uint2*)(dst + (size_t)i * 4) = *(uint2*)o;
        }
        return;
    }
    int z = y - 2;
    const float* S; ushort_t* D; int K_;
    switch (z) {
        case 0: S = s0; D = d0; K_ = 1280; break;
        case 1: S = s1; D = d1; K_ = 2048; break;
        case 2: S = s2; D = d2; K_ = 2048; break;
        case 3: S = s3; D = d3; K_ = 2048; break;
        case 4: S = s4; D = d4; K_ = 2048; break;
        default: S = s5; D = d5; K_ = 1280; break;
    }
    int tr = blockIdx.x / 40, tc = blockIdx.x % 40;
    if (tr >= K_ / 32) return;       // block-uniform early-out (before any barrier)
    __shared__ ushort_t tl[32][33];
    int c = t & 31, r0 = t >> 5;
#pragma unroll
    for (int i = 0; i < 4; i++) {
        int r = r0 + i * 8;
        tl[r][c] = f2bf(S[(size_t)(tr * 32 + r) * 1280 + tc * 32 + c]);
    }
    __syncthreads();
#pragma unroll
    for (int i = 0; i < 4; i++) {
        int r = r0 + i * 8;
        D[(size_t)(tc * 32 + r) * K_ + tr * 32 + c] = tl[c][r];
    }
}

// ---------------- bf16 MFMA GEMM body, B^T layout (N,K), ldc=1280 ----------------
// Direct-register version: no LDS, no barriers. Each wave owns a 64x64 output
// sub-tile of the block's 128x128 tile and reads its A/B fragments straight from
// global memory (contiguous 16B per lane = 16 full 64B lines per instruction).
// Register double-buffer: while MFMAs of half-step k run, loads of k+32 are in
// flight. K/32 is even for all call sites (K = 1280 or 2048).
template <bool F32OUT>
__device__ __forceinline__ void gemm_body(
    const ushort_t* __restrict__ A, const ushort_t* __restrict__ Bt,
    void* __restrict__ Cout, const float* __restrict__ biasf,
    int M, int K, int lda, int row0, int col0)
{
    const int t = threadIdx.x;
    const int w = t >> 6, l = t & 63;
    const int mb = (w >> 1) * 64, nb = (w & 1) * 64;
    const int lrow = l & 15, lk = (l >> 4) * 8;

    // Per-lane fragment base pointers (4 A-frag rows, 4 B-frag rows).
    const ushort_t* pA[4];
    const ushort_t* pB[4];
#pragma unroll
    for (int mt = 0; mt < 4; mt++) {
        int r = row0 + mb + mt * 16 + lrow;
        if (r > M - 1) r = M - 1;                  // clamp (store is row-masked)
        pA[mt] = A + (size_t)r * lda + lk;
    }
#pragma unroll
    for (int nt = 0; nt < 4; nt++) {
        int c = col0 + nb + nt * 16 + lrow;        // N=1280 exact, no clamp needed
        pB[nt] = Bt + (size_t)c * K + lk;
    }

    f32x4 acc[4][4] = {};
    short8 a0[4], b0[4], a1[4], b1[4];

#pragma unroll
    for (int i = 0; i < 4; i++) {
        a0[i] = *(const short8*)(pA[i]);
        b0[i] = *(const short8*)(pB[i]);
    }

    for (int k0 = 0; k0 < K; k0 += 64) {
        // prefetch half-step k0+32 into buffer 1
#pragma unroll
        for (int i = 0; i < 4; i++) {
            a1[i] = *(const short8*)(pA[i] + k0 + 32);
            b1[i] = *(const short8*)(pB[i] + k0 + 32);
        }
        // compute half-step k0 from buffer 0
#pragma unroll
        for (int mt = 0; mt < 4; mt++)
#pragma unroll
            for (int nt = 0; nt < 4; nt++)
                acc[mt][nt] = __builtin_amdgcn_mfma_f32_16x16x32_bf16(
                    a0[mt], b0[nt], acc[mt][nt], 0, 0, 0);
        // prefetch half-step k0+64 into buffer 0 (uniform guard)
        if (k0 + 64 < K) {
#pragma unroll
            for (int i = 0; i < 4; i++) {
                a0[i] = *(const short8*)(pA[i] + k0 + 64);
                b0[i] = *(const short8*)(pB[i] + k0 + 64);
            }
        }
        // compute half-step k0+32 from buffer 1
#pragma unroll
        for (int mt = 0; mt < 4; mt++)
#pragma unroll
            for (int nt = 0; nt < 4; nt++)
                acc[mt][nt] = __builtin_amdgcn_mfma_f32_16x16x32_bf16(
                    a1[mt], b1[nt], acc[mt][nt], 0, 0, 0);
    }

    const int quad = l >> 4, cl = l & 15;
#pragma unroll
    for (int nt = 0; nt < 4; nt++) {
        int col = col0 + nb + nt * 16 + cl;
        float bv = biasf ? biasf[col] : 0.f;
#pragma unroll
        for (int mt = 0; mt < 4; mt++)
#pragma unroll
            for (int r = 0; r < 4; r++) {
                int row = row0 + mb + mt * 16 + quad * 4 + r;
                if (row < M) {
                    if (F32OUT)
                        ((float*)Cout)[(size_t)row * 1280 + col] = acc[mt][nt][r] + bv;
                    else
                        ((ushort_t*)Cout)[(size_t)row * 1280 + col] = f2bf(acc[mt][nt][r] + bv);
                }
            }
    }
}

// q GEMM (x<64) fused with the 8 kv jobs (x=64..71). grid (72,10).
__global__ __launch_bounds__(256, 3) void gemm_q_kv(
    const ushort_t* __restrict__ hsb, const ushort_t* __restrict__ encb,
    const ushort_t* __restrict__ WqT,
    const ushort_t* __restrict__ WkT, const ushort_t* __restrict__ WvT,
    const ushort_t* __restrict__ WknT, const ushort_t* __restrict__ WvnT,
    ushort_t* __restrict__ qb, ushort_t* __restrict__ kb, ushort_t* __restrict__ vb,
    ushort_t* __restrict__ knb, ushort_t* __restrict__ vnb)
{
    int x = blockIdx.x, col0 = blockIdx.y * 128;
    if (x < 64) {
        gemm_body<false>(hsb, WqT, qb, nullptr, B_ * HW_, HID_, HID_, x * 128, col0);
        return;
    }
    int z = x - 64, kind = z & 1;
    const ushort_t* A; const ushort_t* Bt; ushort_t* C; int M;
    if (z < 4) {
        int bb = z >> 1;
        M = LTXT;
        A = encb + (size_t)bb * (LTXT + NTOK) * CAD_;
        Bt = kind ? WvT : WkT;
        C = (kind ? vb : kb) + (size_t)bb * LTXT * HID_;
    } else {
        int bb = (z - 4) >> 1;
        M = NTOK;
        A = encb + ((size_t)bb * (LTXT + NTOK) + LTXT) * CAD_;
        Bt = kind ? WvnT : WknT;
        C = (kind ? vnb : knb) + (size_t)bb * NTOK * HID_;
    }
    gemm_body<false>(A, Bt, C, nullptr, M, CAD_, CAD_, 0, col0);
}

__global__ __launch_bounds__(256, 3) void gemm_bt_f32(
    const ushort_t* __restrict__ A, const ushort_t* __restrict__ Bt,
    float* __restrict__ C, const float* __restrict__ biasf, int M, int K, int lda)
{
    gemm_body<true>(A, Bt, C, biasf, M, K, lda, blockIdx.x * 128, blockIdx.y * 128);
}

// ---------------- fused attention ----------------
// grid: (HW/128, NH, B). block 256 (4 waves x 32 queries).
// 96 padded keys: [0,77)=txt, [77,80)=zero, [80,84)=nested, [84,96)=zero.
// LDS 52.5 KB -> 3 blocks/CU (3 x 52.5 = 157.5 <= 160 KiB).
__global__ __launch_bounds__(256, 3) void attn_kernel(
    const ushort_t* __restrict__ qb, const ushort_t* __restrict__ kbf,
    const ushort_t* __restrict__ vbf, const ushort_t* __restrict__ knb,
    const ushort_t* __restrict__ vnb, const int* __restrict__ sidx,
    ushort_t* __restrict__ ob)
{
    const int qt = blockIdx.x, h = blockIdx.y, b = blockIdx.z;
    const int t = threadIdx.x, w = t >> 6, l = t & 63;
    const int s_idx = sidx[b];
    __shared__ ushort_t Kl[96 * 72];    // key-major, stride 72 (K extent 64 < 72)
    __shared__ ushort_t VT[64 * 104];   // dim-major (V^T), stride 104 (key extent 96 < 104)
    __shared__ ushort_t QP[128 * 104];  // Q phase: stride 72; P phase: stride 104

    // fill K (16B chunks)
    for (int id = t; id < 96 * 8; id += 256) {
        int key = id >> 3, c = (id & 7) * 8;
        uint4 v;
        if (key < LTXT)
            v = *(const uint4*)&kbf[((size_t)(b * LTXT + key)) * HID_ + h * HD_ + c];
        else if (key >= 80 && key < 80 + NTOK)
            v = *(const uint4*)&knb[((size_t)(b * NTOK + key - 80)) * HID_ + h * HD_ + c];
        else
            v = make_uint4(0u, 0u, 0u, 0u);
        *(uint4*)&Kl[key * 72 + c] = v;
    }
    // fill V^T: uint4 global reads (8 dims of one key), scalar LDS writes.
    // Consecutive lanes handle consecutive keys -> LDS writes 2-way aliased (free).
    for (int c8 = (t >> 7); c8 < 8; c8 += 2) {
        int key = t & 127;
        if (key < 96) {
            uint4 v = make_uint4(0u, 0u, 0u, 0u);
            if (key < LTXT)
                v = *(const uint4*)&vbf[((size_t)(b * LTXT + key)) * HID_ + h * HD_ + c8 * 8];
            else if (key >= 80 && key < 80 + NTOK)
                v = *(const uint4*)&vnb[((size_t)(b * NTOK + key - 80)) * HID_ + h * HD_ + c8 * 8];
            ushort_t tmp[8];
            *(uint4*)tmp = v;
#pragma unroll
            for (int j = 0; j < 8; j++)
                VT[(c8 * 8 + j) * 104 + key] = tmp[j];
        }
    }
    // fill Q tile (stride 72)
    const int q0 = qt * 128;
    for (int id = t; id < 128 * 8; id += 256) {
        int r = id >> 3, c = (id & 7) * 8;
        uint4 v = *(const uint4*)&qb[((size_t)(b * HW_ + q0 + r)) * HID_ + h * HD_ + c];
        *(uint4*)&QP[r * 72 + c] = v;
    }
    __syncthreads();

    const int mbw = w * 32, lrow = l & 15, lk = (l >> 4) * 8;
    const int quad = l >> 4, cl = l & 15;

    // S = Q K^T  (M=32 per wave, N=96, K=64)
    f32x4 S[2][6] = {};
#pragma unroll
    for (int ks = 0; ks < 2; ks++) {
        short8 af0 = *(const short8*)&QP[(mbw + lrow) * 72 + ks * 32 + lk];
        short8 af1 = *(const short8*)&QP[(mbw + 16 + lrow) * 72 + ks * 32 + lk];
#pragma unroll
        for (int nt = 0; nt < 6; nt++) {
            short8 bf = *(const short8*)&Kl[(nt * 16 + lrow) * 72 + ks * 32 + lk];
            S[0][nt] = __builtin_amdgcn_mfma_f32_16x16x32_bf16(af0, bf, S[0][nt], 0, 0, 0);
            S[1][nt] = __builtin_amdgcn_mfma_f32_16x16x32_bf16(af1, bf, S[1][nt], 0, 0, 0);
        }
    }
    __syncthreads();  // Q reads done before P overwrites the buffer

    const float sc = 0.125f;
#pragma unroll
    for (int mt = 0; mt < 2; mt++) {
#pragma unroll
        for (int r = 0; r < 4; r++) {
            float v[6];
#pragma unroll
            for (int nt = 0; nt < 6; nt++) v[nt] = S[mt][nt][r] * sc;
            float m = -1e30f;
#pragma unroll
            for (int nt = 0; nt < 5; nt++) {
                int c = nt * 16 + cl;
                if (c < LTXT) m = fmaxf(m, v[nt]);
            }
#pragma unroll
            for (int off = 1; off < 16; off <<= 1) m = fmaxf(m, __shfl_xor(m, off));
            float e[5], lsum = 0.f, wsn = 0.f;
#pragma unroll
            for (int nt = 0; nt < 5; nt++) {
                int c = nt * 16 + cl;
                float ev = (c < LTXT) ? __expf(v[nt] - m) : 0.f;
                e[nt] = ev; lsum += ev;
                if (c == s_idx) wsn += ev;
            }
#pragma unroll
            for (int off = 1; off < 16; off <<= 1) {
                lsum += __shfl_xor(lsum, off);
                wsn  += __shfl_xor(wsn, off);
            }
            float inv = 1.f / lsum;
            float ws = wsn * inv;
            bool nv = (cl < 4);
            float m5 = nv ? v[5] : -1e30f;
#pragma unroll
            for (int off = 1; off < 16; off <<= 1) m5 = fmaxf(m5, __shfl_xor(m5, off));
            float e5 = nv ? __expf(v[5] - m5) : 0.f;
            float l5 = e5;
#pragma unroll
            for (int off = 1; off < 16; off <<= 1) l5 += __shfl_xor(l5, off);
            float p5 = ws * e5 / l5;
            int row = mbw + mt * 16 + quad * 4 + r;
#pragma unroll
            for (int nt = 0; nt < 5; nt++) {
                int c = nt * 16 + cl;
                float p = (c < LTXT && c != s_idx) ? e[nt] * inv : 0.f;
                QP[row * 104 + c] = f2bf(p);
            }
            QP[row * 104 + 80 + cl] = f2bf(p5);
        }
    }
    __syncthreads();

    // O = P @ Vc  (M=32 per wave, N=64, K=96)
    f32x4 O[2][4] = {};
#pragma unroll
    for (int ks = 0; ks < 3; ks++) {
        short8 af0 = *(const short8*)&QP[(mbw + lrow) * 104 + ks * 32 + lk];
        short8 af1 = *(const short8*)&QP[(mbw + 16 + lrow) * 104 + ks * 32 + lk];
#pragma unroll
        for (int nt = 0; nt < 4; nt++) {
            short8 bf = *(const short8*)&VT[(nt * 16 + lrow) * 104 + ks * 32 + lk];
            O[0][nt] = __builtin_amdgcn_mfma_f32_16x16x32_bf16(af0, bf, O[0][nt], 0, 0, 0);
            O[1][nt] = __builtin_amdgcn_mfma_f32_16x16x32_bf16(af1, bf, O[1][nt], 0, 0, 0);
        }
    }
#pragma unroll
    for (int mt = 0; mt < 2; mt++)
#pragma unroll
        for (int nt = 0; nt < 4; nt++)
#pragma unroll
            for (int r = 0; r < 4; r++) {
                int row = mbw + mt * 16 + quad * 4 + r;
                int d = nt * 16 + cl;
                ob[((size_t)(b * HW_ + q0 + row)) * HID_ + h * HD_ + d] = f2bf(O[mt][nt][r]);
            }
}

// ---------------- launch ----------------
extern "C" void kernel_launch(void* const* d_in, const int* in_sizes, int n_in,
                              void* d_out, int out_size, void* d_ws, size_t ws_size,
                              hipStream_t stream) {
    const float* hs   = (const float*)d_in[0];
    const float* enc  = (const float*)d_in[1];
    const int*   idx  = (const int*)d_in[2];
    const float* Wq   = (const float*)d_in[3];
    const float* Wk   = (const float*)d_in[4];
    const float* Wv   = (const float*)d_in[5];
    const float* Wkn  = (const float*)d_in[6];
    const float* Wvn  = (const float*)d_in[7];
    const float* Wout = (const float*)d_in[8];
    const float* bout = (const float*)d_in[9];
    float* out = (float*)d_out;

    ushort_t* ws = (ushort_t*)d_ws;
    size_t o = 0;
    ushort_t* WqT   = ws + o; o += (size_t)1280 * 1280;
    ushort_t* WkT   = ws + o; o += (size_t)1280 * 2048;
    ushort_t* WvT   = ws + o; o += (size_t)1280 * 2048;
    ushort_t* WknT  = ws + o; o += (size_t)1280 * 2048;
    ushort_t* WvnT  = ws + o; o += (size_t)1280 * 2048;
    ushort_t* WoutT = ws + o; o += (size_t)1280 * 1280;
    ushort_t* hsb   = ws + o; o += (size_t)B_ * HW_ * HID_;
    ushort_t* encb  = ws + o; o += (size_t)B_ * (LTXT + NTOK) * CAD_;
    ushort_t* qbuf  = ws + o; o += (size_t)B_ * HW_ * HID_;
    ushort_t* kbuf  = ws + o; o += (size_t)B_ * LTXT * HID_;
    ushort_t* vbuf  = ws + o; o += (size_t)B_ * LTXT * HID_;
    ushort_t* knbuf = ws + o; o += (size_t)B_ * NTOK * HID_;
    ushort_t* vnbuf = ws + o; o += (size_t)B_ * NTOK * HID_;
    ushort_t* attnb = hsb;  // alias: hsb dead after gemm_q_kv

    prep<<<dim3(2560, 8), 256, 0, stream>>>(hs, enc, Wq, Wk, Wv, Wkn, Wvn, Wout,
                                            hsb, encb,
                                            WqT, WkT, WvT, WknT, WvnT, WoutT);
    gemm_q_kv<<<dim3(72, 10), 256, 0, stream>>>(hsb, encb, WqT, WkT, WvT, WknT, WvnT,
                                                qbuf, kbuf, vbuf, knbuf, vnbuf);
    attn_kernel<<<dim3(HW_ / 128, NH_, B_), 256, 0, stream>>>(qbuf, kbuf, vbuf,
                                                              knbuf, vnbuf, idx, attnb);
    gemm_bt_f32<<<dim3(64, 10), 256, 0, stream>>>(attnb, WoutT, out, bout,
                                                  B_ * HW_, HID_, HID_);
}

// Round 4
// 270.466 us; speedup vs baseline: 1.5926x; 1.5926x over previous
//
#include <hip/hip_runtime.h>
#include <hip/hip_bf16.h>

// NestedAttnProcessor: B=2, HW=4096, hid=1280, cad=2048, Ltxt=77, NT=4, H=20, D=64.
// FP32 in/out; bf16 MFMA internally.
// 4 launches: prep(cvt+transpose) -> gemm_q_kv -> attn -> out GEMM.
// R8 vs R7: REVERT direct-register GEMM (142us: scattered 16B frag loads thrashed
//           L1/L2, WRITE_SIZE doubled from partial-line stores). Back to R6's
//           3-buffer counted-vmcnt LDS pipeline (sync structure unchanged), but
//           wave tile widened 64x64 -> 128x64 (BM=256, BN=128, 4 waves 2x2,
//           template<int BM>): LDS-port bytes/FLOP drop 1.33x (port was ~34us of
//           R6's 55us vs 13.7us MFMA floor). kv jobs (M=77/4) keep BM=128 body.
//           LDS 72KB -> 2 blocks/CU, launch_bounds(256,2).

typedef unsigned short ushort_t;
typedef __attribute__((ext_vector_type(8))) short short8;
typedef __attribute__((ext_vector_type(4))) float f32x4;

#define B_   2
#define HW_  4096
#define HID_ 1280
#define CAD_ 2048
#define LTXT 77
#define NTOK 4
#define NH_  20
#define HD_  64

__device__ __forceinline__ ushort_t f2bf(float f) {
    __hip_bfloat16 h = __float2bfloat16(f);
    return *reinterpret_cast<ushort_t*>(&h);
}

__device__ __forceinline__ void gld_lds16(const void* g, void* l) {
    __builtin_amdgcn_global_load_lds(
        (const __attribute__((address_space(1))) unsigned int*)g,
        (__attribute__((address_space(3))) unsigned int*)l,
        16, 0, 0);
}

// ---------------- prep: cvt hs, cvt enc, transpose+cvt 6 weights ----------------
__global__ __launch_bounds__(256) void prep(
    const float* __restrict__ hs, const float* __restrict__ enc,
    const float* __restrict__ s0, const float* __restrict__ s1,
    const float* __restrict__ s2, const float* __restrict__ s3,
    const float* __restrict__ s4, const float* __restrict__ s5,
    ushort_t* __restrict__ hsb, ushort_t* __restrict__ encb,
    ushort_t* __restrict__ d0, ushort_t* __restrict__ d1,
    ushort_t* __restrict__ d2, ushort_t* __restrict__ d3,
    ushort_t* __restrict__ d4, ushort_t* __restrict__ d5)
{
    const int y = blockIdx.y, t = threadIdx.x;
    if (y <= 1) {
        const float* src = y ? enc : hs;
        ushort_t* dst = y ? encb : hsb;
        int n4 = y ? (B_ * (LTXT + NTOK) * CAD_) / 4 : (B_ * HW_ * HID_) / 4;
        int step = gridDim.x * 256;
        for (int i = blockIdx.x * 256 + t; i < n4; i += step) {
            float4 v = *(const float4*)(src + (size_t)i * 4);
            ushort_t o[4] = { f2bf(v.x), f2bf(v.y), f2bf(v.z), f2bf(v.w) };
            *(uint2*)(dst + (size_t)i * 4) = *(uint2*)o;
        }
        return;
    }
    int z = y - 2;
    const float* S; ushort_t* D; int K_;
    switch (z) {
        case 0: S = s0; D = d0; K_ = 1280; break;
        case 1: S = s1; D = d1; K_ = 2048; break;
        case 2: S = s2; D = d2; K_ = 2048; break;
        case 3: S = s3; D = d3; K_ = 2048; break;
        case 4: S = s4; D = d4; K_ = 2048; break;
        default: S = s5; D = d5; K_ = 1280; break;
    }
    int tr = blockIdx.x / 40, tc = blockIdx.x % 40;
    if (tr >= K_ / 32) return;       // block-uniform early-out (before any barrier)
    __shared__ ushort_t tl[32][33];
    int c = t & 31, r0 = t >> 5;
#pragma unroll
    for (int i = 0; i < 4; i++) {
        int r = r0 + i * 8;
        tl[r][c] = f2bf(S[(size_t)(tr * 32 + r) * 1280 + tc * 32 + c]);
    }
    __syncthreads();
#pragma unroll
    for (int i = 0; i < 4; i++) {
        int r = r0 + i * 8;
        D[(size_t)(tc * 32 + r) * K_ + tr * 32 + c] = tl[c][r];
    }
}

// ---------------- bf16 MFMA GEMM body, B^T layout (N,K), ldc=1280 ----------------
// R6-verified schedule: 3 LDS buffers, depth-2 prefetch, counted vmcnt (never 0 in
// the steady loop), raw s_barrier. Templated on BM: 256 -> 4 waves of 128x64 wave
// tiles (2x2); 128 -> R6's original 64x64 tiles. BN = 128 always.
// Steady step t: s_waitcnt vmcnt(LOADS) (tile t landed, t+1 in flight) -> s_barrier
// -> ds_read+MFMA(buf t%3) -> STAGE(tile t+2 into buf (t+2)%3). Last step peeled.
template <int BM, bool F32OUT>
__device__ __forceinline__ void gemm_body(
    const ushort_t* __restrict__ A, const ushort_t* __restrict__ Bt,
    void* __restrict__ Cout, const float* __restrict__ biasf,
    int M, int K, int lda, int row0, int col0, ushort_t* lsbase)
{
    constexpr int MT   = BM / 32;          // A-frags per wave per K-step (8 or 4)
    constexpr int ACH  = BM / 64;          // A chunks per thread per stage (4 or 2)
    constexpr int BUFE = (BM + 128) * 32;  // elems per LDS buffer (A tile + B tile)

    const int t = threadIdx.x;
    const int w = t >> 6, l = t & 63;
    const int wr = (w >> 1) * (BM / 2);    // wave row base (0 / BM/2)
    const int wc = (w & 1) * 64;           // wave col base (0 / 64)
    const int lrow = l & 15, lk = (l >> 4) * 8;

    // Staging: thread t owns 16B chunk c = t + 256*i of each tile.
    // Chunk c -> LDS elems [c*8, c*8+8) -> row c>>2, col (c&3)*8.
    const int r0s = t >> 2, cs = (t & 3) * 8;
    const ushort_t* gA[ACH];
    const ushort_t* gB[2];
#pragma unroll
    for (int i = 0; i < ACH; i++) {
        int r = row0 + r0s + 64 * i;
        if (r > M - 1) r = M - 1;          // clamp (store is row-masked)
        gA[i] = A + (size_t)r * lda + cs;
    }
#pragma unroll
    for (int i = 0; i < 2; i++)
        gB[i] = Bt + (size_t)(col0 + r0s + 64 * i) * K + cs;  // N=1280 exact

#define STAGE_(bf, k0) do { \
        ushort_t* lsA_ = lsbase + (bf) * BUFE; \
        ushort_t* lsB_ = lsA_ + BM * 32; \
        _Pragma("unroll") \
        for (int i = 0; i < ACH; i++) \
            gld_lds16(gA[i] + (k0), lsA_ + (size_t)(t + 256 * i) * 8); \
        _Pragma("unroll") \
        for (int i = 0; i < 2; i++) \
            gld_lds16(gB[i] + (k0), lsB_ + (size_t)(t + 256 * i) * 8); \
    } while (0)

#define COMPUTE_(bf) do { \
        const ushort_t* lsA_ = lsbase + (bf) * BUFE; \
        const ushort_t* lsB_ = lsA_ + BM * 32; \
        short8 af[MT], bfr[4]; \
        _Pragma("unroll") \
        for (int mt = 0; mt < MT; mt++) \
            af[mt] = *(const short8*)&lsA_[(wr + mt * 16 + lrow) * 32 + lk]; \
        _Pragma("unroll") \
        for (int nt = 0; nt < 4; nt++) \
            bfr[nt] = *(const short8*)&lsB_[(wc + nt * 16 + lrow) * 32 + lk]; \
        _Pragma("unroll") \
        for (int mt = 0; mt < MT; mt++) \
            _Pragma("unroll") \
            for (int nt = 0; nt < 4; nt++) \
                acc[mt][nt] = __builtin_amdgcn_mfma_f32_16x16x32_bf16( \
                    af[mt], bfr[nt], acc[mt][nt], 0, 0, 0); \
    } while (0)

    const int nsteps = K / 32;   // >= 40 for all call sites
    f32x4 acc[MT][4] = {};

    STAGE_(0, 0);                // tile 0
    STAGE_(1, 32);               // tile 1 (depth 2 in flight)

    int bsel = 0;
    for (int ts = 0; ts < nsteps - 1; ++ts) {
        // wait: tile ts landed; tile ts+1's LOADS (= ACH+2) stay outstanding
        if constexpr (BM == 256)
            asm volatile("s_waitcnt vmcnt(6)" ::: "memory");
        else
            asm volatile("s_waitcnt vmcnt(4)" ::: "memory");
        __builtin_amdgcn_s_barrier();
        asm volatile("" ::: "memory");
        COMPUTE_(bsel);
        int nx = ts + 2;
        if (nx < nsteps) {
            int nbuf = bsel + 2; if (nbuf >= 3) nbuf -= 3; // buf (ts-1)%3: reads done
            STAGE_(nbuf, nx * 32);
        }
        bsel = bsel + 1; if (bsel >= 3) bsel -= 3;
    }
    // peeled last step: only tile nsteps-1 outstanding -> full drain
    asm volatile("s_waitcnt vmcnt(0)" ::: "memory");
    __builtin_amdgcn_s_barrier();
    asm volatile("" ::: "memory");
    COMPUTE_(bsel);

#undef COMPUTE_
#undef STAGE_

    const int quad = l >> 4, cl = l & 15;
#pragma unroll
    for (int nt = 0; nt < 4; nt++) {
        int col = col0 + wc + nt * 16 + cl;
        float bv = biasf ? biasf[col] : 0.f;
#pragma unroll
        for (int mt = 0; mt < MT; mt++)
#pragma unroll
            for (int r = 0; r < 4; r++) {
                int row = row0 + wr + mt * 16 + quad * 4 + r;
                if (row < M) {
                    if (F32OUT)
                        ((float*)Cout)[(size_t)row * 1280 + col] = acc[mt][nt][r] + bv;
                    else
                        ((ushort_t*)Cout)[(size_t)row * 1280 + col] = f2bf(acc[mt][nt][r] + bv);
                }
            }
    }
}

// q GEMM (x<32, BM=256) fused with the 8 kv jobs (x=32..39, BM=128). grid (40,10).
__global__ __launch_bounds__(256, 2) void gemm_q_kv(
    const ushort_t* __restrict__ hsb, const ushort_t* __restrict__ encb,
    const ushort_t* __restrict__ WqT,
    const ushort_t* __restrict__ WkT, const ushort_t* __restrict__ WvT,
    const ushort_t* __restrict__ WknT, const ushort_t* __restrict__ WvnT,
    ushort_t* __restrict__ qb, ushort_t* __restrict__ kb, ushort_t* __restrict__ vb,
    ushort_t* __restrict__ knb, ushort_t* __restrict__ vnb)
{
    __shared__ ushort_t lds[3 * (256 + 128) * 32];   // 73728 B -> 2 blocks/CU
    int x = blockIdx.x, col0 = blockIdx.y * 128;
    if (x < 32) {
        gemm_body<256, false>(hsb, WqT, qb, nullptr, B_ * HW_, HID_, HID_,
                              x * 256, col0, lds);
        return;
    }
    int z = x - 32, kind = z & 1;
    const ushort_t* A; const ushort_t* Bt; ushort_t* C; int M;
    if (z < 4) {
        int bb = z >> 1;
        M = LTXT;
        A = encb + (size_t)bb * (LTXT + NTOK) * CAD_;
        Bt = kind ? WvT : WkT;
        C = (kind ? vb : kb) + (size_t)bb * LTXT * HID_;
    } else {
        int bb = (z - 4) >> 1;
        M = NTOK;
        A = encb + ((size_t)bb * (LTXT + NTOK) + LTXT) * CAD_;
        Bt = kind ? WvnT : WknT;
        C = (kind ? vnb : knb) + (size_t)bb * NTOK * HID_;
    }
    gemm_body<128, false>(A, Bt, C, nullptr, M, CAD_, CAD_, 0, col0, lds);
}

__global__ __launch_bounds__(256, 2) void gemm_bt_f32(
    const ushort_t* __restrict__ A, const ushort_t* __restrict__ Bt,
    float* __restrict__ C, const float* __restrict__ biasf, int M, int K, int lda)
{
    __shared__ ushort_t lds[3 * (256 + 128) * 32];
    gemm_body<256, true>(A, Bt, C, biasf, M, K, lda,
                         blockIdx.x * 256, blockIdx.y * 128, lds);
}

// ---------------- fused attention ----------------
// grid: (HW/128, NH, B). block 256 (4 waves x 32 queries).
// 96 padded keys: [0,77)=txt, [77,80)=zero, [80,84)=nested, [84,96)=zero.
// LDS 52.5 KB -> 3 blocks/CU (3 x 52.5 = 157.5 <= 160 KiB).
__global__ __launch_bounds__(256, 3) void attn_kernel(
    const ushort_t* __restrict__ qb, const ushort_t* __restrict__ kbf,
    const ushort_t* __restrict__ vbf, const ushort_t* __restrict__ knb,
    const ushort_t* __restrict__ vnb, const int* __restrict__ sidx,
    ushort_t* __restrict__ ob)
{
    const int qt = blockIdx.x, h = blockIdx.y, b = blockIdx.z;
    const int t = threadIdx.x, w = t >> 6, l = t & 63;
    const int s_idx = sidx[b];
    __shared__ ushort_t Kl[96 * 72];    // key-major, stride 72 (K extent 64 < 72)
    __shared__ ushort_t VT[64 * 104];   // dim-major (V^T), stride 104 (key extent 96 < 104)
    __shared__ ushort_t QP[128 * 104];  // Q phase: stride 72; P phase: stride 104

    // fill K (16B chunks)
    for (int id = t; id < 96 * 8; id += 256) {
        int key = id >> 3, c = (id & 7) * 8;
        uint4 v;
        if (key < LTXT)
            v = *(const uint4*)&kbf[((size_t)(b * LTXT + key)) * HID_ + h * HD_ + c];
        else if (key >= 80 && key < 80 + NTOK)
            v = *(const uint4*)&knb[((size_t)(b * NTOK + key - 80)) * HID_ + h * HD_ + c];
        else
            v = make_uint4(0u, 0u, 0u, 0u);
        *(uint4*)&Kl[key * 72 + c] = v;
    }
    // fill V^T: uint4 global reads (8 dims of one key), scalar LDS writes.
    for (int c8 = (t >> 7); c8 < 8; c8 += 2) {
        int key = t & 127;
        if (key < 96) {
            uint4 v = make_uint4(0u, 0u, 0u, 0u);
            if (key < LTXT)
                v = *(const uint4*)&vbf[((size_t)(b * LTXT + key)) * HID_ + h * HD_ + c8 * 8];
            else if (key >= 80 && key < 80 + NTOK)
                v = *(const uint4*)&vnb[((size_t)(b * NTOK + key - 80)) * HID_ + h * HD_ + c8 * 8];
            ushort_t tmp[8];
            *(uint4*)tmp = v;
#pragma unroll
            for (int j = 0; j < 8; j++)
                VT[(c8 * 8 + j) * 104 + key] = tmp[j];
        }
    }
    // fill Q tile (stride 72)
    const int q0 = qt * 128;
    for (int id = t; id < 128 * 8; id += 256) {
        int r = id >> 3, c = (id & 7) * 8;
        uint4 v = *(const uint4*)&qb[((size_t)(b * HW_ + q0 + r)) * HID_ + h * HD_ + c];
        *(uint4*)&QP[r * 72 + c] = v;
    }
    __syncthreads();

    const int mbw = w * 32, lrow = l & 15, lk = (l >> 4) * 8;
    const int quad = l >> 4, cl = l & 15;

    // S = Q K^T  (M=32 per wave, N=96, K=64)
    f32x4 S[2][6] = {};
#pragma unroll
    for (int ks = 0; ks < 2; ks++) {
        short8 af0 = *(const short8*)&QP[(mbw + lrow) * 72 + ks * 32 + lk];
        short8 af1 = *(const short8*)&QP[(mbw + 16 + lrow) * 72 + ks * 32 + lk];
#pragma unroll
        for (int nt = 0; nt < 6; nt++) {
            short8 bf = *(const short8*)&Kl[(nt * 16 + lrow) * 72 + ks * 32 + lk];
            S[0][nt] = __builtin_amdgcn_mfma_f32_16x16x32_bf16(af0, bf, S[0][nt], 0, 0, 0);
            S[1][nt] = __builtin_amdgcn_mfma_f32_16x16x32_bf16(af1, bf, S[1][nt], 0, 0, 0);
        }
    }
    __syncthreads();  // Q reads done before P overwrites the buffer

    const float sc = 0.125f;
#pragma unroll
    for (int mt = 0; mt < 2; mt++) {
#pragma unroll
        for (int r = 0; r < 4; r++) {
            float v[6];
#pragma unroll
            for (int nt = 0; nt < 6; nt++) v[nt] = S[mt][nt][r] * sc;
            float m = -1e30f;
#pragma unroll
            for (int nt = 0; nt < 5; nt++) {
                int c = nt * 16 + cl;
                if (c < LTXT) m = fmaxf(m, v[nt]);
            }
#pragma unroll
            for (int off = 1; off < 16; off <<= 1) m = fmaxf(m, __shfl_xor(m, off));
            float e[5], lsum = 0.f, wsn = 0.f;
#pragma unroll
            for (int nt = 0; nt < 5; nt++) {
                int c = nt * 16 + cl;
                float ev = (c < LTXT) ? __expf(v[nt] - m) : 0.f;
                e[nt] = ev; lsum += ev;
                if (c == s_idx) wsn += ev;
            }
#pragma unroll
            for (int off = 1; off < 16; off <<= 1) {
                lsum += __shfl_xor(lsum, off);
                wsn  += __shfl_xor(wsn, off);
            }
            float inv = 1.f / lsum;
            float ws = wsn * inv;
            bool nv = (cl < 4);
            float m5 = nv ? v[5] : -1e30f;
#pragma unroll
            for (int off = 1; off < 16; off <<= 1) m5 = fmaxf(m5, __shfl_xor(m5, off));
            float e5 = nv ? __expf(v[5] - m5) : 0.f;
            float l5 = e5;
#pragma unroll
            for (int off = 1; off < 16; off <<= 1) l5 += __shfl_xor(l5, off);
            float p5 = ws * e5 / l5;
            int row = mbw + mt * 16 + quad * 4 + r;
#pragma unroll
            for (int nt = 0; nt < 5; nt++) {
                int c = nt * 16 + cl;
                float p = (c < LTXT && c != s_idx) ? e[nt] * inv : 0.f;
                QP[row * 104 + c] = f2bf(p);
            }
            QP[row * 104 + 80 + cl] = f2bf(p5);
        }
    }
    __syncthreads();

    // O = P @ Vc  (M=32 per wave, N=64, K=96)
    f32x4 O[2][4] = {};
#pragma unroll
    for (int ks = 0; ks < 3; ks++) {
        short8 af0 = *(const short8*)&QP[(mbw + lrow) * 104 + ks * 32 + lk];
        short8 af1 = *(const short8*)&QP[(mbw + 16 + lrow) * 104 + ks * 32 + lk];
#pragma unroll
        for (int nt = 0; nt < 4; nt++) {
            short8 bf = *(const short8*)&VT[(nt * 16 + lrow) * 104 + ks * 32 + lk];
            O[0][nt] = __builtin_amdgcn_mfma_f32_16x16x32_bf16(af0, bf, O[0][nt], 0, 0, 0);
            O[1][nt] = __builtin_amdgcn_mfma_f32_16x16x32_bf16(af1, bf, O[1][nt], 0, 0, 0);
        }
    }
#pragma unroll
    for (int mt = 0; mt < 2; mt++)
#pragma unroll
        for (int nt = 0; nt < 4; nt++)
#pragma unroll
            for (int r = 0; r < 4; r++) {
                int row = mbw + mt * 16 + quad * 4 + r;
                int d = nt * 16 + cl;
                ob[((size_t)(b * HW_ + q0 + row)) * HID_ + h * HD_ + d] = f2bf(O[mt][nt][r]);
            }
}

// ---------------- launch ----------------
extern "C" void kernel_launch(void* const* d_in, const int* in_sizes, int n_in,
                              void* d_out, int out_size, void* d_ws, size_t ws_size,
                              hipStream_t stream) {
    const float* hs   = (const float*)d_in[0];
    const float* enc  = (const float*)d_in[1];
    const int*   idx  = (const int*)d_in[2];
    const float* Wq   = (const float*)d_in[3];
    const float* Wk   = (const float*)d_in[4];
    const float* Wv   = (const float*)d_in[5];
    const float* Wkn  = (const float*)d_in[6];
    const float* Wvn  = (const float*)d_in[7];
    const float* Wout = (const float*)d_in[8];
    const float* bout = (const float*)d_in[9];
    float* out = (float*)d_out;

    ushort_t* ws = (ushort_t*)d_ws;
    size_t o = 0;
    ushort_t* WqT   = ws + o; o += (size_t)1280 * 1280;
    ushort_t* WkT   = ws + o; o += (size_t)1280 * 2048;
    ushort_t* WvT   = ws + o; o += (size_t)1280 * 2048;
    ushort_t* WknT  = ws + o; o += (size_t)1280 * 2048;
    ushort_t* WvnT  = ws + o; o += (size_t)1280 * 2048;
    ushort_t* WoutT = ws + o; o += (size_t)1280 * 1280;
    ushort_t* hsb   = ws + o; o += (size_t)B_ * HW_ * HID_;
    ushort_t* encb  = ws + o; o += (size_t)B_ * (LTXT + NTOK) * CAD_;
    ushort_t* qbuf  = ws + o; o += (size_t)B_ * HW_ * HID_;
    ushort_t* kbuf  = ws + o; o += (size_t)B_ * LTXT * HID_;
    ushort_t* vbuf  = ws + o; o += (size_t)B_ * LTXT * HID_;
    ushort_t* knbuf = ws + o; o += (size_t)B_ * NTOK * HID_;
    ushort_t* vnbuf = ws + o; o += (size_t)B_ * NTOK * HID_;
    ushort_t* attnb = hsb;  // alias: hsb dead after gemm_q_kv

    prep<<<dim3(2560, 8), 256, 0, stream>>>(hs, enc, Wq, Wk, Wv, Wkn, Wvn, Wout,
                                            hsb, encb,
                                            WqT, WkT, WvT, WknT, WvnT, WoutT);
    gemm_q_kv<<<dim3(40, 10), 256, 0, stream>>>(hsb, encb, WqT, WkT, WvT, WknT, WvnT,
                                                qbuf, kbuf, vbuf, knbuf, vnbuf);
    attn_kernel<<<dim3(HW_ / 128, NH_, B_), 256, 0, stream>>>(qbuf, kbuf, vbuf,
                                                              knbuf, vnbuf, idx, attnb);
    gemm_bt_f32<<<dim3(32, 10), 256, 0, stream>>>(attnb, WoutT, out, bout,
                                                  B_ * HW_, HID_, HID_);
}

// Round 5
// 268.397 us; speedup vs baseline: 1.6049x; 1.0077x over previous
//
#include <hip/hip_runtime.h>
#include <hip/hip_bf16.h>

// NestedAttnProcessor: B=2, HW=4096, hid=1280, cad=2048, Ltxt=77, NT=4, H=20, D=64.
// FP32 in/out; bf16 MFMA internally.
// 4 launches: prep(cvt+transpose) -> gemm_q_kv -> attn -> out GEMM.
// R9 vs R8: (1) bt_f32 reverted to BM=128 (grid 640, 3 blocks/CU): BM=256's
//           320-block grid left 8 waves/CU + a 64-CU tail -> 60us regression.
//           q GEMM keeps BM=256 (46us, -9 vs R6: LDS-port-bytes model held).
//           (2) prep weight transpose vectorized: float4 reads, LDS 32x34
//           (odd-word stride, <=2-way conflicts), uint2 writes — was scalar
//           f32 reads + scalar bf16 writes (Common-mistake #2; prep ~55us vs
//           22us floor). (3) attn nested-softmax: 2-shfl 4-lane-group reduce
//           + nv guard on p5 (guards 0/0 NaN).

typedef unsigned short ushort_t;
typedef __attribute__((ext_vector_type(8))) short short8;
typedef __attribute__((ext_vector_type(4))) float f32x4;

#define B_   2
#define HW_  4096
#define HID_ 1280
#define CAD_ 2048
#define LTXT 77
#define NTOK 4
#define NH_  20
#define HD_  64

__device__ __forceinline__ ushort_t f2bf(float f) {
    __hip_bfloat16 h = __float2bfloat16(f);
    return *reinterpret_cast<ushort_t*>(&h);
}

__device__ __forceinline__ void gld_lds16(const void* g, void* l) {
    __builtin_amdgcn_global_load_lds(
        (const __attribute__((address_space(1))) unsigned int*)g,
        (__attribute__((address_space(3))) unsigned int*)l,
        16, 0, 0);
}

// ---------------- prep: cvt hs, cvt enc, transpose+cvt 6 weights ----------------
// grid (2560, 8): y=0 hs cvt (grid-stride), y=1 enc cvt (grid-stride),
//                 y=2..7 weight transpose (z=y-2), 32x32 tiles, vectorized.
__global__ __launch_bounds__(256) void prep(
    const float* __restrict__ hs, const float* __restrict__ enc,
    const float* __restrict__ s0, const float* __restrict__ s1,
    const float* __restrict__ s2, const float* __restrict__ s3,
    const float* __restrict__ s4, const float* __restrict__ s5,
    ushort_t* __restrict__ hsb, ushort_t* __restrict__ encb,
    ushort_t* __restrict__ d0, ushort_t* __restrict__ d1,
    ushort_t* __restrict__ d2, ushort_t* __restrict__ d3,
    ushort_t* __restrict__ d4, ushort_t* __restrict__ d5)
{
    const int y = blockIdx.y, t = threadIdx.x;
    if (y <= 1) {
        const float* src = y ? enc : hs;
        ushort_t* dst = y ? encb : hsb;
        int n4 = y ? (B_ * (LTXT + NTOK) * CAD_) / 4 : (B_ * HW_ * HID_) / 4;
        int step = gridDim.x * 256;
        for (int i = blockIdx.x * 256 + t; i < n4; i += step) {
            float4 v = *(const float4*)(src + (size_t)i * 4);
            ushort_t o[4] = { f2bf(v.x), f2bf(v.y), f2bf(v.z), f2bf(v.w) };
            *(uint2*)(dst + (size_t)i * 4) = *(uint2*)o;
        }
        return;
    }
    int z = y - 2;
    const float* S; ushort_t* D; int K_;
    switch (z) {
        case 0: S = s0; D = d0; K_ = 1280; break;
        case 1: S = s1; D = d1; K_ = 2048; break;
        case 2: S = s2; D = d2; K_ = 2048; break;
        case 3: S = s3; D = d3; K_ = 2048; break;
        case 4: S = s4; D = d4; K_ = 2048; break;
        default: S = s5; D = d5; K_ = 1280; break;
    }
    int tr = blockIdx.x / 40, tc = blockIdx.x % 40;
    if (tr >= K_ / 32) return;       // block-uniform early-out (before any barrier)

    // Vectorized 32x32 transpose. Read: thread (r = t>>3, c4 = (t&7)*4) loads
    // float4 -> 4 bf16 -> two aligned u32 LDS writes (row stride 34 ushorts =
    // 17 words, odd -> <=2-way bank aliasing = free). Write: thread gathers
    // column rout = t>>3, elems 4j..4j+3 (j = t&7) -> one uint2 global store.
    __shared__ ushort_t tl[32][34];
    const int r = t >> 3, j = t & 7, c4 = j * 4;
    float4 v = *(const float4*)&S[(size_t)(tr * 32 + r) * 1280 + tc * 32 + c4];
    ushort_t o[4] = { f2bf(v.x), f2bf(v.y), f2bf(v.z), f2bf(v.w) };
    *(uint*)&tl[r][c4]     = *(uint*)&o[0];
    *(uint*)&tl[r][c4 + 2] = *(uint*)&o[2];
    __syncthreads();
    ushort_t p[4];
#pragma unroll
    for (int i = 0; i < 4; i++) p[i] = tl[4 * j + i][r];
    *(uint2*)&D[(size_t)(tc * 32 + r) * K_ + tr * 32 + 4 * j] = *(uint2*)p;
}

// ---------------- bf16 MFMA GEMM body, B^T layout (N,K), ldc=1280 ----------------
// R6-verified schedule: 3 LDS buffers, depth-2 prefetch, counted vmcnt (never 0 in
// the steady loop), raw s_barrier. Templated on BM: 256 -> 4 waves of 128x64 wave
// tiles (2x2); 128 -> 64x64 tiles. BN = 128 always.
// Steady step t: s_waitcnt vmcnt(LOADS) (tile t landed, t+1 in flight) -> s_barrier
// -> ds_read+MFMA(buf t%3) -> STAGE(tile t+2 into buf (t+2)%3). Last step peeled.
template <int BM, bool F32OUT>
__device__ __forceinline__ void gemm_body(
    const ushort_t* __restrict__ A, const ushort_t* __restrict__ Bt,
    void* __restrict__ Cout, const float* __restrict__ biasf,
    int M, int K, int lda, int row0, int col0, ushort_t* lsbase)
{
    constexpr int MT   = BM / 32;          // A-frags per wave per K-step (8 or 4)
    constexpr int ACH  = BM / 64;          // A chunks per thread per stage (4 or 2)
    constexpr int BUFE = (BM + 128) * 32;  // elems per LDS buffer (A tile + B tile)

    const int t = threadIdx.x;
    const int w = t >> 6, l = t & 63;
    const int wr = (w >> 1) * (BM / 2);    // wave row base (0 / BM/2)
    const int wc = (w & 1) * 64;           // wave col base (0 / 64)
    const int lrow = l & 15, lk = (l >> 4) * 8;

    // Staging: thread t owns 16B chunk c = t + 256*i of each tile.
    // Chunk c -> LDS elems [c*8, c*8+8) -> row c>>2, col (c&3)*8.
    const int r0s = t >> 2, cs = (t & 3) * 8;
    const ushort_t* gA[ACH];
    const ushort_t* gB[2];
#pragma unroll
    for (int i = 0; i < ACH; i++) {
        int r = row0 + r0s + 64 * i;
        if (r > M - 1) r = M - 1;          // clamp (store is row-masked)
        gA[i] = A + (size_t)r * lda + cs;
    }
#pragma unroll
    for (int i = 0; i < 2; i++)
        gB[i] = Bt + (size_t)(col0 + r0s + 64 * i) * K + cs;  // N=1280 exact

#define STAGE_(bf, k0) do { \
        ushort_t* lsA_ = lsbase + (bf) * BUFE; \
        ushort_t* lsB_ = lsA_ + BM * 32; \
        _Pragma("unroll") \
        for (int i = 0; i < ACH; i++) \
            gld_lds16(gA[i] + (k0), lsA_ + (size_t)(t + 256 * i) * 8); \
        _Pragma("unroll") \
        for (int i = 0; i < 2; i++) \
            gld_lds16(gB[i] + (k0), lsB_ + (size_t)(t + 256 * i) * 8); \
    } while (0)

#define COMPUTE_(bf) do { \
        const ushort_t* lsA_ = lsbase + (bf) * BUFE; \
        const ushort_t* lsB_ = lsA_ + BM * 32; \
        short8 af[MT], bfr[4]; \
        _Pragma("unroll") \
        for (int mt = 0; mt < MT; mt++) \
            af[mt] = *(const short8*)&lsA_[(wr + mt * 16 + lrow) * 32 + lk]; \
        _Pragma("unroll") \
        for (int nt = 0; nt < 4; nt++) \
            bfr[nt] = *(const short8*)&lsB_[(wc + nt * 16 + lrow) * 32 + lk]; \
        _Pragma("unroll") \
        for (int mt = 0; mt < MT; mt++) \
            _Pragma("unroll") \
            for (int nt = 0; nt < 4; nt++) \
                acc[mt][nt] = __builtin_amdgcn_mfma_f32_16x16x32_bf16( \
                    af[mt], bfr[nt], acc[mt][nt], 0, 0, 0); \
    } while (0)

    const int nsteps = K / 32;   // >= 40 for all call sites
    f32x4 acc[MT][4] = {};

    STAGE_(0, 0);                // tile 0
    STAGE_(1, 32);               // tile 1 (depth 2 in flight)

    int bsel = 0;
    for (int ts = 0; ts < nsteps - 1; ++ts) {
        // wait: tile ts landed; tile ts+1's LOADS (= ACH+2) stay outstanding
        if constexpr (BM == 256)
            asm volatile("s_waitcnt vmcnt(6)" ::: "memory");
        else
            asm volatile("s_waitcnt vmcnt(4)" ::: "memory");
        __builtin_amdgcn_s_barrier();
        asm volatile("" ::: "memory");
        COMPUTE_(bsel);
        int nx = ts + 2;
        if (nx < nsteps) {
            int nbuf = bsel + 2; if (nbuf >= 3) nbuf -= 3; // buf (ts-1)%3: reads done
            STAGE_(nbuf, nx * 32);
        }
        bsel = bsel + 1; if (bsel >= 3) bsel -= 3;
    }
    // peeled last step: only tile nsteps-1 outstanding -> full drain
    asm volatile("s_waitcnt vmcnt(0)" ::: "memory");
    __builtin_amdgcn_s_barrier();
    asm volatile("" ::: "memory");
    COMPUTE_(bsel);

#undef COMPUTE_
#undef STAGE_

    const int quad = l >> 4, cl = l & 15;
#pragma unroll
    for (int nt = 0; nt < 4; nt++) {
        int col = col0 + wc + nt * 16 + cl;
        float bv = biasf ? biasf[col] : 0.f;
#pragma unroll
        for (int mt = 0; mt < MT; mt++)
#pragma unroll
            for (int r = 0; r < 4; r++) {
                int row = row0 + wr + mt * 16 + quad * 4 + r;
                if (row < M) {
                    if (F32OUT)
                        ((float*)Cout)[(size_t)row * 1280 + col] = acc[mt][nt][r] + bv;
                    else
                        ((ushort_t*)Cout)[(size_t)row * 1280 + col] = f2bf(acc[mt][nt][r] + bv);
                }
            }
    }
}

// q GEMM (x<32, BM=256) fused with the 8 kv jobs (x=32..39, BM=128). grid (40,10).
__global__ __launch_bounds__(256, 2) void gemm_q_kv(
    const ushort_t* __restrict__ hsb, const ushort_t* __restrict__ encb,
    const ushort_t* __restrict__ WqT,
    const ushort_t* __restrict__ WkT, const ushort_t* __restrict__ WvT,
    const ushort_t* __restrict__ WknT, const ushort_t* __restrict__ WvnT,
    ushort_t* __restrict__ qb, ushort_t* __restrict__ kb, ushort_t* __restrict__ vb,
    ushort_t* __restrict__ knb, ushort_t* __restrict__ vnb)
{
    __shared__ ushort_t lds[3 * (256 + 128) * 32];   // 73728 B -> 2 blocks/CU
    int x = blockIdx.x, col0 = blockIdx.y * 128;
    if (x < 32) {
        gemm_body<256, false>(hsb, WqT, qb, nullptr, B_ * HW_, HID_, HID_,
                              x * 256, col0, lds);
        return;
    }
    int z = x - 32, kind = z & 1;
    const ushort_t* A; const ushort_t* Bt; ushort_t* C; int M;
    if (z < 4) {
        int bb = z >> 1;
        M = LTXT;
        A = encb + (size_t)bb * (LTXT + NTOK) * CAD_;
        Bt = kind ? WvT : WkT;
        C = (kind ? vb : kb) + (size_t)bb * LTXT * HID_;
    } else {
        int bb = (z - 4) >> 1;
        M = NTOK;
        A = encb + ((size_t)bb * (LTXT + NTOK) + LTXT) * CAD_;
        Bt = kind ? WvnT : WknT;
        C = (kind ? vnb : knb) + (size_t)bb * NTOK * HID_;
    }
    gemm_body<128, false>(A, Bt, C, nullptr, M, CAD_, CAD_, 0, col0, lds);
}

// BM=128: grid (64,10) = 640 blocks, 48KB LDS -> 3 blocks/CU (R6-verified config).
__global__ __launch_bounds__(256, 3) void gemm_bt_f32(
    const ushort_t* __restrict__ A, const ushort_t* __restrict__ Bt,
    float* __restrict__ C, const float* __restrict__ biasf, int M, int K, int lda)
{
    __shared__ ushort_t lds[3 * (128 + 128) * 32];
    gemm_body<128, true>(A, Bt, C, biasf, M, K, lda,
                         blockIdx.x * 128, blockIdx.y * 128, lds);
}

// ---------------- fused attention ----------------
// grid: (HW/128, NH, B). block 256 (4 waves x 32 queries).
// 96 padded keys: [0,77)=txt, [77,80)=zero, [80,84)=nested, [84,96)=zero.
// LDS 52.5 KB -> 3 blocks/CU (3 x 52.5 = 157.5 <= 160 KiB).
__global__ __launch_bounds__(256, 3) void attn_kernel(
    const ushort_t* __restrict__ qb, const ushort_t* __restrict__ kbf,
    const ushort_t* __restrict__ vbf, const ushort_t* __restrict__ knb,
    const ushort_t* __restrict__ vnb, const int* __restrict__ sidx,
    ushort_t* __restrict__ ob)
{
    const int qt = blockIdx.x, h = blockIdx.y, b = blockIdx.z;
    const int t = threadIdx.x, w = t >> 6, l = t & 63;
    const int s_idx = sidx[b];
    __shared__ ushort_t Kl[96 * 72];    // key-major, stride 72 (K extent 64 < 72)
    __shared__ ushort_t VT[64 * 104];   // dim-major (V^T), stride 104 (key extent 96 < 104)
    __shared__ ushort_t QP[128 * 104];  // Q phase: stride 72; P phase: stride 104

    // fill K (16B chunks)
    for (int id = t; id < 96 * 8; id += 256) {
        int key = id >> 3, c = (id & 7) * 8;
        uint4 v;
        if (key < LTXT)
            v = *(const uint4*)&kbf[((size_t)(b * LTXT + key)) * HID_ + h * HD_ + c];
        else if (key >= 80 && key < 80 + NTOK)
            v = *(const uint4*)&knb[((size_t)(b * NTOK + key - 80)) * HID_ + h * HD_ + c];
        else
            v = make_uint4(0u, 0u, 0u, 0u);
        *(uint4*)&Kl[key * 72 + c] = v;
    }
    // fill V^T: uint4 global reads (8 dims of one key), scalar LDS writes.
    for (int c8 = (t >> 7); c8 < 8; c8 += 2) {
        int key = t & 127;
        if (key < 96) {
            uint4 v = make_uint4(0u, 0u, 0u, 0u);
            if (key < LTXT)
                v = *(const uint4*)&vbf[((size_t)(b * LTXT + key)) * HID_ + h * HD_ + c8 * 8];
            else if (key >= 80 && key < 80 + NTOK)
                v = *(const uint4*)&vnb[((size_t)(b * NTOK + key - 80)) * HID_ + h * HD_ + c8 * 8];
            ushort_t tmp[8];
            *(uint4*)tmp = v;
#pragma unroll
            for (int j = 0; j < 8; j++)
                VT[(c8 * 8 + j) * 104 + key] = tmp[j];
        }
    }
    // fill Q tile (stride 72)
    const int q0 = qt * 128;
    for (int id = t; id < 128 * 8; id += 256) {
        int r = id >> 3, c = (id & 7) * 8;
        uint4 v = *(const uint4*)&qb[((size_t)(b * HW_ + q0 + r)) * HID_ + h * HD_ + c];
        *(uint4*)&QP[r * 72 + c] = v;
    }
    __syncthreads();

    const int mbw = w * 32, lrow = l & 15, lk = (l >> 4) * 8;
    const int quad = l >> 4, cl = l & 15;

    // S = Q K^T  (M=32 per wave, N=96, K=64)
    f32x4 S[2][6] = {};
#pragma unroll
    for (int ks = 0; ks < 2; ks++) {
        short8 af0 = *(const short8*)&QP[(mbw + lrow) * 72 + ks * 32 + lk];
        short8 af1 = *(const short8*)&QP[(mbw + 16 + lrow) * 72 + ks * 32 + lk];
#pragma unroll
        for (int nt = 0; nt < 6; nt++) {
            short8 bf = *(const short8*)&Kl[(nt * 16 + lrow) * 72 + ks * 32 + lk];
            S[0][nt] = __builtin_amdgcn_mfma_f32_16x16x32_bf16(af0, bf, S[0][nt], 0, 0, 0);
            S[1][nt] = __builtin_amdgcn_mfma_f32_16x16x32_bf16(af1, bf, S[1][nt], 0, 0, 0);
        }
    }
    __syncthreads();  // Q reads done before P overwrites the buffer

    const float sc = 0.125f;
#pragma unroll
    for (int mt = 0; mt < 2; mt++) {
#pragma unroll
        for (int r = 0; r < 4; r++) {
            float v[6];
#pragma unroll
            for (int nt = 0; nt < 6; nt++) v[nt] = S[mt][nt][r] * sc;
            float m = -1e30f;
#pragma unroll
            for (int nt = 0; nt < 5; nt++) {
                int c = nt * 16 + cl;
                if (c < LTXT) m = fmaxf(m, v[nt]);
            }
#pragma unroll
            for (int off = 1; off < 16; off <<= 1) m = fmaxf(m, __shfl_xor(m, off));
            float e[5], lsum = 0.f, wsn = 0.f;
#pragma unroll
            for (int nt = 0; nt < 5; nt++) {
                int c = nt * 16 + cl;
                float ev = (c < LTXT) ? __expf(v[nt] - m) : 0.f;
                e[nt] = ev; lsum += ev;
                if (c == s_idx) wsn += ev;
            }
#pragma unroll
            for (int off = 1; off < 16; off <<= 1) {
                lsum += __shfl_xor(lsum, off);
                wsn  += __shfl_xor(wsn, off);
            }
            float inv = 1.f / lsum;
            float ws = wsn * inv;
            // nested branch: valid lanes cl<4 form one aligned 4-lane XOR group
            // within each 16-lane row-group -> 2-shfl reduce; guard p5 (lanes
            // cl>=4 have l5=0 -> 0/0 NaN without the guard; their columns hit
            // zero V rows but NaN*0=NaN, so must write 0).
            bool nv = (cl < 4);
            float m5 = nv ? v[5] : -1e30f;
#pragma unroll
            for (int off = 1; off < 4; off <<= 1) m5 = fmaxf(m5, __shfl_xor(m5, off));
            float e5 = nv ? __expf(v[5] - m5) : 0.f;
            float l5 = e5;
#pragma unroll
            for (int off = 1; off < 4; off <<= 1) l5 += __shfl_xor(l5, off);
            float p5 = nv ? (ws * e5 / l5) : 0.f;
            int row = mbw + mt * 16 + quad * 4 + r;
#pragma unroll
            for (int nt = 0; nt < 5; nt++) {
                int c = nt * 16 + cl;
                float p = (c < LTXT && c != s_idx) ? e[nt] * inv : 0.f;
                QP[row * 104 + c] = f2bf(p);
            }
            QP[row * 104 + 80 + cl] = f2bf(p5);
        }
    }
    __syncthreads();

    // O = P @ Vc  (M=32 per wave, N=64, K=96)
    f32x4 O[2][4] = {};
#pragma unroll
    for (int ks = 0; ks < 3; ks++) {
        short8 af0 = *(const short8*)&QP[(mbw + lrow) * 104 + ks * 32 + lk];
        short8 af1 = *(const short8*)&QP[(mbw + 16 + lrow) * 104 + ks * 32 + lk];
#pragma unroll
        for (int nt = 0; nt < 4; nt++) {
            short8 bf = *(const short8*)&VT[(nt * 16 + lrow) * 104 + ks * 32 + lk];
            O[0][nt] = __builtin_amdgcn_mfma_f32_16x16x32_bf16(af0, bf, O[0][nt], 0, 0, 0);
            O[1][nt] = __builtin_amdgcn_mfma_f32_16x16x32_bf16(af1, bf, O[1][nt], 0, 0, 0);
        }
    }
#pragma unroll
    for (int mt = 0; mt < 2; mt++)
#pragma unroll
        for (int nt = 0; nt < 4; nt++)
#pragma unroll
            for (int r = 0; r < 4; r++) {
                int row = mbw + mt * 16 + quad * 4 + r;
                int d = nt * 16 + cl;
                ob[((size_t)(b * HW_ + q0 + row)) * HID_ + h * HD_ + d] = f2bf(O[mt][nt][r]);
            }
}

// ---------------- launch ----------------
extern "C" void kernel_launch(void* const* d_in, const int* in_sizes, int n_in,
                              void* d_out, int out_size, void* d_ws, size_t ws_size,
                              hipStream_t stream) {
    const float* hs   = (const float*)d_in[0];
    const float* enc  = (const float*)d_in[1];
    const int*   idx  = (const int*)d_in[2];
    const float* Wq   = (const float*)d_in[3];
    const float* Wk   = (const float*)d_in[4];
    const float* Wv   = (const float*)d_in[5];
    const float* Wkn  = (const float*)d_in[6];
    const float* Wvn  = (const float*)d_in[7];
    const float* Wout = (const float*)d_in[8];
    const float* bout = (const float*)d_in[9];
    float* out = (float*)d_out;

    ushort_t* ws = (ushort_t*)d_ws;
    size_t o = 0;
    ushort_t* WqT   = ws + o; o += (size_t)1280 * 1280;
    ushort_t* WkT   = ws + o; o += (size_t)1280 * 2048;
    ushort_t* WvT   = ws + o; o += (size_t)1280 * 2048;
    ushort_t* WknT  = ws + o; o += (size_t)1280 * 2048;
    ushort_t* WvnT  = ws + o; o += (size_t)1280 * 2048;
    ushort_t* WoutT = ws + o; o += (size_t)1280 * 1280;
    ushort_t* hsb   = ws + o; o += (size_t)B_ * HW_ * HID_;
    ushort_t* encb  = ws + o; o += (size_t)B_ * (LTXT + NTOK) * CAD_;
    ushort_t* qbuf  = ws + o; o += (size_t)B_ * HW_ * HID_;
    ushort_t* kbuf  = ws + o; o += (size_t)B_ * LTXT * HID_;
    ushort_t* vbuf  = ws + o; o += (size_t)B_ * LTXT * HID_;
    ushort_t* knbuf = ws + o; o += (size_t)B_ * NTOK * HID_;
    ushort_t* vnbuf = ws + o; o += (size_t)B_ * NTOK * HID_;
    ushort_t* attnb = hsb;  // alias: hsb dead after gemm_q_kv

    prep<<<dim3(2560, 8), 256, 0, stream>>>(hs, enc, Wq, Wk, Wv, Wkn, Wvn, Wout,
                                            hsb, encb,
                                            WqT, WkT, WvT, WknT, WvnT, WoutT);
    gemm_q_kv<<<dim3(40, 10), 256, 0, stream>>>(hsb, encb, WqT, WkT, WvT, WknT, WvnT,
                                                qbuf, kbuf, vbuf, knbuf, vnbuf);
    attn_kernel<<<dim3(HW_ / 128, NH_, B_), 256, 0, stream>>>(qbuf, kbuf, vbuf,
                                                              knbuf, vnbuf, idx, attnb);
    gemm_bt_f32<<<dim3(64, 10), 256, 0, stream>>>(attnb, WoutT, out, bout,
                                                  B_ * HW_, HID_, HID_);
}

// Round 7
// 266.826 us; speedup vs baseline: 1.6143x; 1.0059x over previous
//
#include <hip/hip_runtime.h>
#include <hip/hip_bf16.h>

// NestedAttnProcessor: B=2, HW=4096, hid=1280, cad=2048, Ltxt=77, NT=4, H=20, D=64.
// FP32 in/out; bf16 MFMA internally.
// 4 launches: prep(cvt+transpose) -> gemm_q_kv -> attn -> out GEMM.
// R11 vs R10: R10 bundled 3 changes and hit the nondeterminism tripwire. Bisect:
//             GEMM body and attn reverted EXACTLY to R9 (verified-good, 268us);
//             only the prep change is kept (transpose blocks 4x fatter: 32x128
//             per block, 4 sub-tiles, one barrier; 20480 -> 5120 blocks; theory:
//             transpose jobs dispatch/latency-bound at 1 float4/thread).
//             If tripwire persists -> prep is the culprit; if it passes and total
//             drops ~10us -> prep latency theory confirmed, attn/GEMM-reorder
//             get re-examined individually later.

typedef unsigned short ushort_t;
typedef __attribute__((ext_vector_type(8))) short short8;
typedef __attribute__((ext_vector_type(4))) float f32x4;

#define B_   2
#define HW_  4096
#define HID_ 1280
#define CAD_ 2048
#define LTXT 77
#define NTOK 4
#define NH_  20
#define HD_  64

__device__ __forceinline__ ushort_t f2bf(float f) {
    __hip_bfloat16 h = __float2bfloat16(f);
    return *reinterpret_cast<ushort_t*>(&h);
}

__device__ __forceinline__ void gld_lds16(const void* g, void* l) {
    __builtin_amdgcn_global_load_lds(
        (const __attribute__((address_space(1))) unsigned int*)g,
        (__attribute__((address_space(3))) unsigned int*)l,
        16, 0, 0);
}

// ---------------- prep: cvt hs, cvt enc, transpose+cvt 6 weights ----------------
// grid (640, 8): y=0 hs cvt (grid-stride), y=1 enc cvt (grid-stride),
//                y=2..7 weight transpose (z=y-2), 32x128 per block (4 sub-tiles).
__global__ __launch_bounds__(256) void prep(
    const float* __restrict__ hs, const float* __restrict__ enc,
    const float* __restrict__ s0, const float* __restrict__ s1,
    const float* __restrict__ s2, const float* __restrict__ s3,
    const float* __restrict__ s4, const float* __restrict__ s5,
    ushort_t* __restrict__ hsb, ushort_t* __restrict__ encb,
    ushort_t* __restrict__ d0, ushort_t* __restrict__ d1,
    ushort_t* __restrict__ d2, ushort_t* __restrict__ d3,
    ushort_t* __restrict__ d4, ushort_t* __restrict__ d5)
{
    const int y = blockIdx.y, t = threadIdx.x;
    if (y <= 1) {
        const float* src = y ? enc : hs;
        ushort_t* dst = y ? encb : hsb;
        int n4 = y ? (B_ * (LTXT + NTOK) * CAD_) / 4 : (B_ * HW_ * HID_) / 4;
        int step = gridDim.x * 256;
        for (int i = blockIdx.x * 256 + t; i < n4; i += step) {
            float4 v = *(const float4*)(src + (size_t)i * 4);
            ushort_t o[4] = { f2bf(v.x), f2bf(v.y), f2bf(v.z), f2bf(v.w) };
            *(uint2*)(dst + (size_t)i * 4) = *(uint2*)o;
        }
        return;
    }
    int z = y - 2;
    const float* S; ushort_t* D; int K_;
    switch (z) {
        case 0: S = s0; D = d0; K_ = 1280; break;
        case 1: S = s1; D = d1; K_ = 2048; break;
        case 2: S = s2; D = d2; K_ = 2048; break;
        case 3: S = s3; D = d3; K_ = 2048; break;
        case 4: S = s4; D = d4; K_ = 2048; break;
        default: S = s5; D = d5; K_ = 1280; break;
    }
    // 32 rows x 128 cols per block: tr = row-tile, tc4 = 128-col group (10 per row).
    int tr = blockIdx.x / 10, tc4 = blockIdx.x % 10;
    if (tr >= K_ / 32) return;       // block-uniform early-out (before any barrier)

    // 4 independent 32x32 sub-tile transposes. Read: thread (r=t>>3, j=t&7) loads
    // float4 from sub-tile i -> 4 bf16 -> two u32 LDS writes (row stride 34
    // ushorts = 17 words, odd -> conflict-light). Write: gather 4 rows of column
    // r -> one uint2 global store per sub-tile.
    __shared__ ushort_t tl[4][32][34];
    const int r = t >> 3, j = t & 7, c4 = j * 4;
#pragma unroll
    for (int i = 0; i < 4; i++) {
        float4 v = *(const float4*)&S[(size_t)(tr * 32 + r) * 1280 + tc4 * 128 + i * 32 + c4];
        ushort_t o[4] = { f2bf(v.x), f2bf(v.y), f2bf(v.z), f2bf(v.w) };
        *(uint*)&tl[i][r][c4]     = *(uint*)&o[0];
        *(uint*)&tl[i][r][c4 + 2] = *(uint*)&o[2];
    }
    __syncthreads();
#pragma unroll
    for (int i = 0; i < 4; i++) {
        ushort_t p[4];
#pragma unroll
        for (int k = 0; k < 4; k++) p[k] = tl[i][4 * j + k][r];
        *(uint2*)&D[(size_t)(tc4 * 128 + i * 32 + r) * K_ + tr * 32 + 4 * j] = *(uint2*)p;
    }
}

// ---------------- bf16 MFMA GEMM body, B^T layout (N,K), ldc=1280 ----------------
// R9-verified schedule (restored exactly): 3 LDS buffers, depth-2 prefetch,
// counted vmcnt (never 0 in the steady loop), raw s_barrier, COMPUTE then STAGE.
// BM=256 -> 4 waves of 128x64 tiles; BM=128 -> 64x64. BN=128.
template <int BM, bool F32OUT>
__device__ __forceinline__ void gemm_body(
    const ushort_t* __restrict__ A, const ushort_t* __restrict__ Bt,
    void* __restrict__ Cout, const float* __restrict__ biasf,
    int M, int K, int lda, int row0, int col0, ushort_t* lsbase)
{
    constexpr int MT   = BM / 32;          // A-frags per wave per K-step (8 or 4)
    constexpr int ACH  = BM / 64;          // A chunks per thread per stage (4 or 2)
    constexpr int BUFE = (BM + 128) * 32;  // elems per LDS buffer (A tile + B tile)

    const int t = threadIdx.x;
    const int w = t >> 6, l = t & 63;
    const int wr = (w >> 1) * (BM / 2);    // wave row base (0 / BM/2)
    const int wc = (w & 1) * 64;           // wave col base (0 / 64)
    const int lrow = l & 15, lk = (l >> 4) * 8;

    // Staging: thread t owns 16B chunk c = t + 256*i of each tile.
    const int r0s = t >> 2, cs = (t & 3) * 8;
    const ushort_t* gA[ACH];
    const ushort_t* gB[2];
#pragma unroll
    for (int i = 0; i < ACH; i++) {
        int r = row0 + r0s + 64 * i;
        if (r > M - 1) r = M - 1;          // clamp (store is row-masked)
        gA[i] = A + (size_t)r * lda + cs;
    }
#pragma unroll
    for (int i = 0; i < 2; i++)
        gB[i] = Bt + (size_t)(col0 + r0s + 64 * i) * K + cs;  // N=1280 exact

#define STAGE_(bf, k0) do { \
        ushort_t* lsA_ = lsbase + (bf) * BUFE; \
        ushort_t* lsB_ = lsA_ + BM * 32; \
        _Pragma("unroll") \
        for (int i = 0; i < ACH; i++) \
            gld_lds16(gA[i] + (k0), lsA_ + (size_t)(t + 256 * i) * 8); \
        _Pragma("unroll") \
        for (int i = 0; i < 2; i++) \
            gld_lds16(gB[i] + (k0), lsB_ + (size_t)(t + 256 * i) * 8); \
    } while (0)

#define COMPUTE_(bf) do { \
        const ushort_t* lsA_ = lsbase + (bf) * BUFE; \
        const ushort_t* lsB_ = lsA_ + BM * 32; \
        short8 af[MT], bfr[4]; \
        _Pragma("unroll") \
        for (int mt = 0; mt < MT; mt++) \
            af[mt] = *(const short8*)&lsA_[(wr + mt * 16 + lrow) * 32 + lk]; \
        _Pragma("unroll") \
        for (int nt = 0; nt < 4; nt++) \
            bfr[nt] = *(const short8*)&lsB_[(wc + nt * 16 + lrow) * 32 + lk]; \
        _Pragma("unroll") \
        for (int mt = 0; mt < MT; mt++) \
            _Pragma("unroll") \
            for (int nt = 0; nt < 4; nt++) \
                acc[mt][nt] = __builtin_amdgcn_mfma_f32_16x16x32_bf16( \
                    af[mt], bfr[nt], acc[mt][nt], 0, 0, 0); \
    } while (0)

    const int nsteps = K / 32;   // >= 40 for all call sites
    f32x4 acc[MT][4] = {};

    STAGE_(0, 0);                // tile 0
    STAGE_(1, 32);               // tile 1 (depth 2 in flight)

    int bsel = 0;
    for (int ts = 0; ts < nsteps - 1; ++ts) {
        // wait: tile ts landed; tile ts+1's LOADS (= ACH+2) stay outstanding
        if constexpr (BM == 256)
            asm volatile("s_waitcnt vmcnt(6)" ::: "memory");
        else
            asm volatile("s_waitcnt vmcnt(4)" ::: "memory");
        __builtin_amdgcn_s_barrier();
        asm volatile("" ::: "memory");
        COMPUTE_(bsel);
        int nx = ts + 2;
        if (nx < nsteps) {
            int nbuf = bsel + 2; if (nbuf >= 3) nbuf -= 3; // buf (ts-1)%3: reads done
            STAGE_(nbuf, nx * 32);
        }
        bsel = bsel + 1; if (bsel >= 3) bsel -= 3;
    }
    // peeled last step: only tile nsteps-1 outstanding -> full drain
    asm volatile("s_waitcnt vmcnt(0)" ::: "memory");
    __builtin_amdgcn_s_barrier();
    asm volatile("" ::: "memory");
    COMPUTE_(bsel);

#undef COMPUTE_
#undef STAGE_

    const int quad = l >> 4, cl = l & 15;
#pragma unroll
    for (int nt = 0; nt < 4; nt++) {
        int col = col0 + wc + nt * 16 + cl;
        float bv = biasf ? biasf[col] : 0.f;
#pragma unroll
        for (int mt = 0; mt < MT; mt++)
#pragma unroll
            for (int r = 0; r < 4; r++) {
                int row = row0 + wr + mt * 16 + quad * 4 + r;
                if (row < M) {
                    if (F32OUT)
                        ((float*)Cout)[(size_t)row * 1280 + col] = acc[mt][nt][r] + bv;
                    else
                        ((ushort_t*)Cout)[(size_t)row * 1280 + col] = f2bf(acc[mt][nt][r] + bv);
                }
            }
    }
}

// q GEMM (x<32, BM=256) fused with the 8 kv jobs (x=32..39, BM=128). grid (40,10).
__global__ __launch_bounds__(256, 2) void gemm_q_kv(
    const ushort_t* __restrict__ hsb, const ushort_t* __restrict__ encb,
    const ushort_t* __restrict__ WqT,
    const ushort_t* __restrict__ WkT, const ushort_t* __restrict__ WvT,
    const ushort_t* __restrict__ WknT, const ushort_t* __restrict__ WvnT,
    ushort_t* __restrict__ qb, ushort_t* __restrict__ kb, ushort_t* __restrict__ vb,
    ushort_t* __restrict__ knb, ushort_t* __restrict__ vnb)
{
    __shared__ ushort_t lds[3 * (256 + 128) * 32];   // 73728 B -> 2 blocks/CU
    int x = blockIdx.x, col0 = blockIdx.y * 128;
    if (x < 32) {
        gemm_body<256, false>(hsb, WqT, qb, nullptr, B_ * HW_, HID_, HID_,
                              x * 256, col0, lds);
        return;
    }
    int z = x - 32, kind = z & 1;
    const ushort_t* A; const ushort_t* Bt; ushort_t* C; int M;
    if (z < 4) {
        int bb = z >> 1;
        M = LTXT;
        A = encb + (size_t)bb * (LTXT + NTOK) * CAD_;
        Bt = kind ? WvT : WkT;
        C = (kind ? vb : kb) + (size_t)bb * LTXT * HID_;
    } else {
        int bb = (z - 4) >> 1;
        M = NTOK;
        A = encb + ((size_t)bb * (LTXT + NTOK) + LTXT) * CAD_;
        Bt = kind ? WvnT : WknT;
        C = (kind ? vnb : knb) + (size_t)bb * NTOK * HID_;
    }
    gemm_body<128, false>(A, Bt, C, nullptr, M, CAD_, CAD_, 0, col0, lds);
}

// BM=128: grid (64,10) = 640 blocks, 48KB LDS -> 3 blocks/CU (R6-verified config).
__global__ __launch_bounds__(256, 3) void gemm_bt_f32(
    const ushort_t* __restrict__ A, const ushort_t* __restrict__ Bt,
    float* __restrict__ C, const float* __restrict__ biasf, int M, int K, int lda)
{
    __shared__ ushort_t lds[3 * (128 + 128) * 32];
    gemm_body<128, true>(A, Bt, C, biasf, M, K, lda,
                         blockIdx.x * 128, blockIdx.y * 128, lds);
}

// ---------------- fused attention ----------------
// grid: (HW/128, NH, B). block 256 (4 waves x 32 queries). (R9-verified, restored.)
// 96 padded keys: [0,77)=txt, [77,80)=zero, [80,84)=nested, [84,96)=zero.
// LDS 52.5 KB -> 3 blocks/CU (3 x 52.5 = 157.5 <= 160 KiB).
__global__ __launch_bounds__(256, 3) void attn_kernel(
    const ushort_t* __restrict__ qb, const ushort_t* __restrict__ kbf,
    const ushort_t* __restrict__ vbf, const ushort_t* __restrict__ knb,
    const ushort_t* __restrict__ vnb, const int* __restrict__ sidx,
    ushort_t* __restrict__ ob)
{
    const int qt = blockIdx.x, h = blockIdx.y, b = blockIdx.z;
    const int t = threadIdx.x, w = t >> 6, l = t & 63;
    const int s_idx = sidx[b];
    __shared__ ushort_t Kl[96 * 72];    // key-major, stride 72 (K extent 64 < 72)
    __shared__ ushort_t VT[64 * 104];   // dim-major (V^T), stride 104 (key extent 96 < 104)
    __shared__ ushort_t QP[128 * 104];  // Q phase: stride 72; P phase: stride 104

    // fill K (16B chunks)
    for (int id = t; id < 96 * 8; id += 256) {
        int key = id >> 3, c = (id & 7) * 8;
        uint4 v;
        if (key < LTXT)
            v = *(const uint4*)&kbf[((size_t)(b * LTXT + key)) * HID_ + h * HD_ + c];
        else if (key >= 80 && key < 80 + NTOK)
            v = *(const uint4*)&knb[((size_t)(b * NTOK + key - 80)) * HID_ + h * HD_ + c];
        else
            v = make_uint4(0u, 0u, 0u, 0u);
        *(uint4*)&Kl[key * 72 + c] = v;
    }
    // fill V^T: uint4 global reads (8 dims of one key), scalar LDS writes.
    for (int c8 = (t >> 7); c8 < 8; c8 += 2) {
        int key = t & 127;
        if (key < 96) {
            uint4 v = make_uint4(0u, 0u, 0u, 0u);
            if (key < LTXT)
                v = *(const uint4*)&vbf[((size_t)(b * LTXT + key)) * HID_ + h * HD_ + c8 * 8];
            else if (key >= 80 && key < 80 + NTOK)
                v = *(const uint4*)&vnb[((size_t)(b * NTOK + key - 80)) * HID_ + h * HD_ + c8 * 8];
            ushort_t tmp[8];
            *(uint4*)tmp = v;
#pragma unroll
            for (int j = 0; j < 8; j++)
                VT[(c8 * 8 + j) * 104 + key] = tmp[j];
        }
    }
    // fill Q tile (stride 72)
    const int q0 = qt * 128;
    for (int id = t; id < 128 * 8; id += 256) {
        int r = id >> 3, c = (id & 7) * 8;
        uint4 v = *(const uint4*)&qb[((size_t)(b * HW_ + q0 + r)) * HID_ + h * HD_ + c];
        *(uint4*)&QP[r * 72 + c] = v;
    }
    __syncthreads();

    const int mbw = w * 32, lrow = l & 15, lk = (l >> 4) * 8;
    const int quad = l >> 4, cl = l & 15;

    // S = Q K^T  (M=32 per wave, N=96, K=64)
    f32x4 S[2][6] = {};
#pragma unroll
    for (int ks = 0; ks < 2; ks++) {
        short8 af0 = *(const short8*)&QP[(mbw + lrow) * 72 + ks * 32 + lk];
        short8 af1 = *(const short8*)&QP[(mbw + 16 + lrow) * 72 + ks * 32 + lk];
#pragma unroll
        for (int nt = 0; nt < 6; nt++) {
            short8 bf = *(const short8*)&Kl[(nt * 16 + lrow) * 72 + ks * 32 + lk];
            S[0][nt] = __builtin_amdgcn_mfma_f32_16x16x32_bf16(af0, bf, S[0][nt], 0, 0, 0);
            S[1][nt] = __builtin_amdgcn_mfma_f32_16x16x32_bf16(af1, bf, S[1][nt], 0, 0, 0);
        }
    }
    __syncthreads();  // Q reads done before P overwrites the buffer

    const float sc = 0.125f;
#pragma unroll
    for (int mt = 0; mt < 2; mt++) {
#pragma unroll
        for (int r = 0; r < 4; r++) {
            float v[6];
#pragma unroll
            for (int nt = 0; nt < 6; nt++) v[nt] = S[mt][nt][r] * sc;
            float m = -1e30f;
#pragma unroll
            for (int nt = 0; nt < 5; nt++) {
                int c = nt * 16 + cl;
                if (c < LTXT) m = fmaxf(m, v[nt]);
            }
#pragma unroll
            for (int off = 1; off < 16; off <<= 1) m = fmaxf(m, __shfl_xor(m, off));
            float e[5], lsum = 0.f, wsn = 0.f;
#pragma unroll
            for (int nt = 0; nt < 5; nt++) {
                int c = nt * 16 + cl;
                float ev = (c < LTXT) ? __expf(v[nt] - m) : 0.f;
                e[nt] = ev; lsum += ev;
                if (c == s_idx) wsn += ev;
            }
#pragma unroll
            for (int off = 1; off < 16; off <<= 1) {
                lsum += __shfl_xor(lsum, off);
                wsn  += __shfl_xor(wsn, off);
            }
            float inv = 1.f / lsum;
            float ws = wsn * inv;
            // nested branch: valid lanes cl<4 form one aligned 4-lane XOR group
            // within each 16-lane row-group -> 2-shfl reduce; guard p5 (lanes
            // cl>=4 have l5=0 -> 0/0 NaN without the guard).
            bool nv = (cl < 4);
            float m5 = nv ? v[5] : -1e30f;
#pragma unroll
            for (int off = 1; off < 4; off <<= 1) m5 = fmaxf(m5, __shfl_xor(m5, off));
            float e5 = nv ? __expf(v[5] - m5) : 0.f;
            float l5 = e5;
#pragma unroll
            for (int off = 1; off < 4; off <<= 1) l5 += __shfl_xor(l5, off);
            float p5 = nv ? (ws * e5 / l5) : 0.f;
            int row = mbw + mt * 16 + quad * 4 + r;
#pragma unroll
            for (int nt = 0; nt < 5; nt++) {
                int c = nt * 16 + cl;
                float p = (c < LTXT && c != s_idx) ? e[nt] * inv : 0.f;
                QP[row * 104 + c] = f2bf(p);
            }
            QP[row * 104 + 80 + cl] = f2bf(p5);
        }
    }
    __syncthreads();

    // O = P @ Vc  (M=32 per wave, N=64, K=96)
    f32x4 O[2][4] = {};
#pragma unroll
    for (int ks = 0; ks < 3; ks++) {
        short8 af0 = *(const short8*)&QP[(mbw + lrow) * 104 + ks * 32 + lk];
        short8 af1 = *(const short8*)&QP[(mbw + 16 + lrow) * 104 + ks * 32 + lk];
#pragma unroll
        for (int nt = 0; nt < 4; nt++) {
            short8 bf = *(const short8*)&VT[(nt * 16 + lrow) * 104 + ks * 32 + lk];
            O[0][nt] = __builtin_amdgcn_mfma_f32_16x16x32_bf16(af0, bf, O[0][nt], 0, 0, 0);
            O[1][nt] = __builtin_amdgcn_mfma_f32_16x16x32_bf16(af1, bf, O[1][nt], 0, 0, 0);
        }
    }
#pragma unroll
    for (int mt = 0; mt < 2; mt++)
#pragma unroll
        for (int nt = 0; nt < 4; nt++)
#pragma unroll
            for (int r = 0; r < 4; r++) {
                int row = mbw + mt * 16 + quad * 4 + r;
                int d = nt * 16 + cl;
                ob[((size_t)(b * HW_ + q0 + row)) * HID_ + h * HD_ + d] = f2bf(O[mt][nt][r]);
            }
}

// ---------------- launch ----------------
extern "C" void kernel_launch(void* const* d_in, const int* in_sizes, int n_in,
                              void* d_out, int out_size, void* d_ws, size_t ws_size,
                              hipStream_t stream) {
    const float* hs   = (const float*)d_in[0];
    const float* enc  = (const float*)d_in[1];
    const int*   idx  = (const int*)d_in[2];
    const float* Wq   = (const float*)d_in[3];
    const float* Wk   = (const float*)d_in[4];
    const float* Wv   = (const float*)d_in[5];
    const float* Wkn  = (const float*)d_in[6];
    const float* Wvn  = (const float*)d_in[7];
    const float* Wout = (const float*)d_in[8];
    const float* bout = (const float*)d_in[9];
    float* out = (float*)d_out;

    ushort_t* ws = (ushort_t*)d_ws;
    size_t o = 0;
    ushort_t* WqT   = ws + o; o += (size_t)1280 * 1280;
    ushort_t* WkT   = ws + o; o += (size_t)1280 * 2048;
    ushort_t* WvT   = ws + o; o += (size_t)1280 * 2048;
    ushort_t* WknT  = ws + o; o += (size_t)1280 * 2048;
    ushort_t* WvnT  = ws + o; o += (size_t)1280 * 2048;
    ushort_t* WoutT = ws + o; o += (size_t)1280 * 1280;
    ushort_t* hsb   = ws + o; o += (size_t)B_ * HW_ * HID_;
    ushort_t* encb  = ws + o; o += (size_t)B_ * (LTXT + NTOK) * CAD_;
    ushort_t* qbuf  = ws + o; o += (size_t)B_ * HW_ * HID_;
    ushort_t* kbuf  = ws + o; o += (size_t)B_ * LTXT * HID_;
    ushort_t* vbuf  = ws + o; o += (size_t)B_ * LTXT * HID_;
    ushort_t* knbuf = ws + o; o += (size_t)B_ * NTOK * HID_;
    ushort_t* vnbuf = ws + o; o += (size_t)B_ * NTOK * HID_;
    ushort_t* attnb = hsb;  // alias: hsb dead after gemm_q_kv

    prep<<<dim3(640, 8), 256, 0, stream>>>(hs, enc, Wq, Wk, Wv, Wkn, Wvn, Wout,
                                           hsb, encb,
                                           WqT, WkT, WvT, WknT, WvnT, WoutT);
    gemm_q_kv<<<dim3(40, 10), 256, 0, stream>>>(hsb, encb, WqT, WkT, WvT, WknT, WvnT,
                                                qbuf, kbuf, vbuf, knbuf, vnbuf);
    attn_kernel<<<dim3(HW_ / 128, NH_, B_), 256, 0, stream>>>(qbuf, kbuf, vbuf,
                                                              knbuf, vnbuf, idx, attnb);
    gemm_bt_f32<<<dim3(64, 10), 256, 0, stream>>>(attnb, WoutT, out, bout,
                                                  B_ * HW_, HID_, HID_);
}